// Round 1
// 1103.087 us; speedup vs baseline: 1.0298x; 1.0298x over previous
//
#include <hip/hip_runtime.h>

typedef unsigned short u16;
typedef unsigned int u32;
typedef __attribute__((ext_vector_type(8))) short bf16x8;
typedef __attribute__((ext_vector_type(4))) float f32x4;

#define MFMA(a, b, c) __builtin_amdgcn_mfma_f32_16x16x32_bf16(a, b, c, 0, 0, 0)

__device__ __forceinline__ u16 f2bf(float x) {
    union { float f; u32 u; } v; v.f = x;
    u32 r = (v.u + 0x7FFFu + ((v.u >> 16) & 1u)) >> 16;
    return (u16)r;
}
__device__ __forceinline__ float bf2f(u16 b) {
    union { u32 u; float f; } v; v.u = ((u32)b) << 16;
    return v.f;
}
__device__ __forceinline__ void casAddPair(u32* w, float lo, float hi) {
    u32 old = *w, assumed;
    do {
        assumed = old;
        u32 des = (u32)f2bf(bf2f((u16)(assumed & 0xFFFFu)) + lo) |
                  ((u32)f2bf(bf2f((u16)(assumed >> 16)) + hi) << 16);
        if (des == assumed) break;
        old = atomicCAS(w, assumed, des);
    } while (old != assumed);
}

// ---------------------------------------------------------------------------
// prep: convert LSTM weights to bf16, combine biases.
// Pre-scale by log2(e) (g-gate rows by 2*log2(e)) so lstm3 can use native
// v_exp_f32 (2^x) with free negation modifiers.
__global__ __launch_bounds__(256) void prep_w(
    const float* __restrict__ Whh_f, const float* __restrict__ Whh_b,
    const float* __restrict__ Wih_f, const float* __restrict__ Wih_b,
    const float* __restrict__ bih_f, const float* __restrict__ bhh_f,
    const float* __restrict__ bih_b, const float* __restrict__ bhh_b,
    u16* __restrict__ WhhB, u16* __restrict__ WihB, float* __restrict__ BS)
{
    const float L2E = 1.4426950408889634f;
    int i = blockIdx.x * 256 + threadIdx.x;
    if (i < 131072) {
        int d = i >> 16, r = i & 65535;
        float s = (((r >> 14) & 3) == 2) ? 2.f * L2E : L2E;   // gate row = r>>7, gate = row>>7
        WhhB[i] = f2bf(s * (d ? Whh_b[r] : Whh_f[r]));
    } else if (i < 196608) {
        int i2 = i - 131072; int d = i2 >> 15, r = i2 & 32767;
        float s = (((r >> 13) & 3) == 2) ? 2.f * L2E : L2E;
        WihB[i2] = f2bf(s * (d ? Wih_b[r] : Wih_f[r]));
    } else if (i < 197632) {
        int i3 = i - 196608; int d = i3 >> 9, g = i3 & 511;
        float s = (((g >> 7) & 3) == 2) ? 2.f * L2E : L2E;
        BS[i3] = s * (d ? (bih_b[g] + bhh_b[g]) : (bih_f[g] + bhh_f[g]));
    }
}

// ---------------------------------------------------------------------------
// CSR build
__global__ __launch_bounds__(256) void count_kernel(const int* __restrict__ dst,
                                                    u32* __restrict__ cnt, long E)
{
    long i = (long)blockIdx.x * 256 + threadIdx.x;
    if (i < E) atomicAdd(&cnt[dst[i]], 1u);
}

__global__ __launch_bounds__(256) void scan1(const u32* __restrict__ a,
                                             u32* __restrict__ part, int n)
{
    __shared__ u32 ts[256];
    int b = blockIdx.x, t = threadIdx.x;
    long i0 = (long)b * 1024 + t * 4;
    u32 s = 0;
#pragma unroll
    for (int k = 0; k < 4; ++k) { long i = i0 + k; if (i < n) s += a[i]; }
    ts[t] = s; __syncthreads();
    for (int off = 1; off < 256; off <<= 1) {
        u32 x = (t >= off) ? ts[t - off] : 0u;
        __syncthreads(); ts[t] += x; __syncthreads();
    }
    if (t == 255) part[b] = ts[255];
}

__global__ __launch_bounds__(1024) void scan2(u32* __restrict__ part, int nb,
                                              u32* __restrict__ total_out)
{
    __shared__ u32 ts[1024];
    int t = threadIdx.x;
    u32 v = (t < nb) ? part[t] : 0u;
    ts[t] = v; __syncthreads();
    for (int off = 1; off < 1024; off <<= 1) {
        u32 x = (t >= off) ? ts[t - off] : 0u;
        __syncthreads(); ts[t] += x; __syncthreads();
    }
    if (t < nb) part[t] = ts[t] - v;
    if (t == 1023 && total_out) *total_out = ts[1023];
}

__global__ __launch_bounds__(256) void scan3(u32* __restrict__ a,
                                             const u32* __restrict__ part, int n)
{
    __shared__ u32 ts[256];
    int b = blockIdx.x, t = threadIdx.x;
    long i0 = (long)b * 1024 + t * 4;
    u32 v[4]; u32 s = 0;
#pragma unroll
    for (int k = 0; k < 4; ++k) { long i = i0 + k; v[k] = (i < n) ? a[i] : 0u; s += v[k]; }
    ts[t] = s; __syncthreads();
    for (int off = 1; off < 256; off <<= 1) {
        u32 x = (t >= off) ? ts[t - off] : 0u;
        __syncthreads(); ts[t] += x; __syncthreads();
    }
    u32 run = part[b] + ts[t] - s;
#pragma unroll
    for (int k = 0; k < 4; ++k) {
        long i = i0 + k;
        if (i < n) { u32 x = v[k]; a[i] = run; run += x; }
    }
}

__global__ __launch_bounds__(256) void fill_kernel(const int* __restrict__ dst,
                                                   u32* __restrict__ off,
                                                   int* __restrict__ list, long E)
{
    long i = (long)blockIdx.x * 256 + threadIdx.x;
    if (i < E) {
        u32 pos = atomicAdd(&off[dst[i]], 1u);
        list[pos] = (int)i;
    }
}

// ---------------------------------------------------------------------------
// zero_fill: zero only rows needing init (empty buckets + buckets crossing a
// 128-position block boundary, which are CAS-accumulated).
__global__ __launch_bounds__(256) void zero_fill(const u32* __restrict__ offc,
                                                 u16* __restrict__ outb, long NB)
{
    long idx = (long)blockIdx.x * 256 + threadIdx.x;
    long n = idx >> 3; int q = (int)(idx & 7);
    if (n >= NB) return;
    u32 s = n ? offc[n - 1] : 0u;
    u32 e = offc[n];
    bool need = (s == e) || ((s >> 7) != ((e - 1) >> 7));
    if (need) *(uint4*)(outb + n * 64 + q * 8) = make_uint4(0, 0, 0, 0);
}

// ---------------------------------------------------------------------------
// rowgemm: outb[M x 64] (bf16) = act(in[M x K] @ W[64 x K]^T (+ bias*scale))
template <int K, bool RELU, bool INBF16>
__global__ __launch_bounds__(256) void rowgemm(
    const void* __restrict__ in, const float* __restrict__ W,
    const float* __restrict__ bias, const float* __restrict__ bias_scale,
    u16* __restrict__ outb, int M)
{
    constexpr int KP = K + 8;
    __shared__ u16 inS[64 * KP];
    __shared__ u16 WS[64 * KP];
    int t = threadIdx.x;
    long rb = (long)blockIdx.x * 64;
    for (int i = t; i < 64 * K; i += 256) {
        int c = i / K, k = i - c * K;
        WS[c * KP + k] = f2bf(W[i]);
    }
    if (INBF16) {
        const u16* inb = (const u16*)in;
        for (int i = t; i < 64 * K / 8; i += 256) {
            int r = i / (K / 8), q = i - r * (K / 8);
            long gr = rb + r;
            uint4 v = make_uint4(0, 0, 0, 0);
            if (gr < M) v = *(const uint4*)&inb[gr * (long)K + q * 8];
            *(uint4*)&inS[r * KP + q * 8] = v;
        }
    } else {
        const float* inf = (const float*)in;
        for (int i = t; i < 64 * K; i += 256) {
            int r = i / K, k = i - r * K;
            long gr = rb + r;
            inS[r * KP + k] = (gr < M) ? f2bf(inf[gr * (long)K + k]) : (u16)0;
        }
    }
    __syncthreads();
    int l = t & 63, w = t >> 6, lr = l & 15, lq = l >> 4;
    f32x4 acc[4];
#pragma unroll
    for (int i = 0; i < 4; ++i) acc[i] = (f32x4){0.f, 0.f, 0.f, 0.f};
#pragma unroll
    for (int kc = 0; kc < K; kc += 32) {
        bf16x8 a = *(const bf16x8*)&inS[(w * 16 + lr) * KP + kc + lq * 8];
#pragma unroll
        for (int ct = 0; ct < 4; ++ct) {
            bf16x8 b = *(const bf16x8*)&WS[(ct * 16 + lr) * KP + kc + lq * 8];
            acc[ct] = MFMA(a, b, acc[ct]);
        }
    }
#pragma unroll
    for (int ct = 0; ct < 4; ++ct)
#pragma unroll
        for (int r = 0; r < 4; ++r) {
            long gr = rb + w * 16 + lq * 4 + r;
            if (gr < M) {
                int c = ct * 16 + lr;
                float v = acc[ct][r];
                if (bias) v += bias[c] * (bias_scale ? bias_scale[gr] : 1.f);
                if (RELU) v = fmaxf(v, 0.f);
                outb[gr * 64 + c] = f2bf(v);
            }
        }
}

// ---------------------------------------------------------------------------
// edge_msg_init2: direct-gather A-fragments (no inS staging).
__global__ __launch_bounds__(512, 4) void edge_msg_init2(
    const u16* __restrict__ feat, const int* __restrict__ ei,
    const float* __restrict__ attr, const float* __restrict__ W,
    u16* __restrict__ outb, long E)
{
    __shared__ u16 WS[64 * 168];
    __shared__ u16 eds[128 * 64];
    int t = threadIdx.x;
    long eb = (long)blockIdx.x * 128;
    for (int i = t; i < 64 * 144; i += 512) {
        int c = i / 144, k = i - c * 144;
        WS[c * 168 + k] = f2bf(W[i]);
    }
    for (int i = t; i < 64 * 24; i += 512) {
        int c = i / 24, k = 144 + (i - c * 24);
        WS[c * 168 + k] = 0;
    }
    int w = t >> 6, l = t & 63, lr = l & 15, lq = l >> 4;
    long e = eb + w * 16 + lr;
    long ec = (e < E) ? e : (E - 1);
    int src = ei[ec], dst = ei[E + ec];
    bf16x8 A[5];
    {
        const uint4* sp = (const uint4*)(feat + (long)src * 64);
        const uint4* dp = (const uint4*)(feat + (long)dst * 64);
        *(uint4*)&A[0] = sp[lq];
        *(uint4*)&A[1] = sp[4 + lq];
        *(uint4*)&A[2] = dp[lq];
        *(uint4*)&A[3] = dp[4 + lq];
        uint4 pv = make_uint4(0, 0, 0, 0);
        if (lq < 2) {
            const float4* ap = (const float4*)(attr + ec * 16) + lq * 2;
            float4 b0 = ap[0], b1 = ap[1];
            pv.x = (u32)f2bf(b0.x) | ((u32)f2bf(b0.y) << 16);
            pv.y = (u32)f2bf(b0.z) | ((u32)f2bf(b0.w) << 16);
            pv.z = (u32)f2bf(b1.x) | ((u32)f2bf(b1.y) << 16);
            pv.w = (u32)f2bf(b1.z) | ((u32)f2bf(b1.w) << 16);
        }
        *(uint4*)&A[4] = pv;
    }
    __syncthreads();
    f32x4 acc[4];
#pragma unroll
    for (int ct = 0; ct < 4; ++ct) acc[ct] = (f32x4){0.f, 0.f, 0.f, 0.f};
#pragma unroll
    for (int kc = 0; kc < 5; ++kc) {
#pragma unroll
        for (int ct = 0; ct < 4; ++ct) {
            bf16x8 b = *(const bf16x8*)&WS[(ct * 16 + lr) * 168 + kc * 32 + lq * 8];
            acc[ct] = MFMA(A[kc], b, acc[ct]);
        }
    }
#pragma unroll
    for (int ct = 0; ct < 4; ++ct)
#pragma unroll
        for (int r = 0; r < 4; ++r) {
            int row = w * 16 + lq * 4 + r;
            int col = ct * 16 + lr;
            eds[row * 64 + col] = f2bf(fmaxf(acc[ct][r], 0.f));
        }
    __syncthreads();
    for (int j = t; j < 1024; j += 512) {
        int le = j >> 3, q = j & 7;
        long e2 = eb + le;
        if (e2 < E)
            *(uint4*)(outb + e2 * 64 + q * 8) = *(const uint4*)&eds[le * 64 + q * 8];
    }
}

// ---------------------------------------------------------------------------
// edge_msg_lg2: direct-gather A-frags, dst-sorted (CSR) order, segmented
// reduction epilogue (plain store for intra-block segments, CAS at borders).
__global__ __launch_bounds__(512, 4) void edge_msg_lg2(
    const u16* __restrict__ feat, const int* __restrict__ ei,
    const float* __restrict__ attr, const float* __restrict__ W,
    const int* __restrict__ list, u16* __restrict__ outb, long E)
{
    __shared__ u16 WS[64 * 168];
    __shared__ u16 eds[128 * 64];
    __shared__ int dstS[128];
    __shared__ int idS[128];
    __shared__ int srcS[128];
    __shared__ int dprevS, dnextS;
    int t = threadIdx.x;
    long pb = (long)blockIdx.x * 128;
    for (int i = t; i < 64 * 144; i += 512) {
        int c = i / 144, k = i - c * 144;
        WS[c * 168 + k] = f2bf(W[i]);
    }
    for (int i = t; i < 64 * 24; i += 512) {
        int c = i / 24, k = 144 + (i - c * 24);
        WS[c * 168 + k] = 0;
    }
    if (t < 128) {
        long p = pb + t;
        int id = (p < E) ? list[p] : -1;
        idS[t] = id;
        srcS[t] = (id >= 0) ? ei[id] : 0;
        dstS[t] = (id >= 0) ? ei[E + id] : -1;
    } else if (t == 128) {
        dprevS = (pb > 0) ? ei[E + list[pb - 1]] : -2;
    } else if (t == 129) {
        dnextS = (pb + 128 < E) ? ei[E + list[pb + 128]] : -2;
    }
    __syncthreads();
    int w = t >> 6, l = t & 63, lr = l & 15, lq = l >> 4;
    int el = w * 16 + lr;
    int id = idS[el];
    long idc = (id >= 0) ? (long)id : 0;
    int src = srcS[el];
    int dst = (dstS[el] >= 0) ? dstS[el] : 0;
    bf16x8 A[5];
    {
        const uint4* sp = (const uint4*)(feat + (long)src * 64);
        const uint4* dp = (const uint4*)(feat + (long)dst * 64);
        *(uint4*)&A[0] = sp[lq];
        *(uint4*)&A[1] = sp[4 + lq];
        *(uint4*)&A[2] = dp[lq];
        *(uint4*)&A[3] = dp[4 + lq];
        uint4 pv = make_uint4(0, 0, 0, 0);
        if (lq < 2) {
            const float4* ap = (const float4*)(attr + idc * 16) + lq * 2;
            float4 b0 = ap[0], b1 = ap[1];
            pv.x = (u32)f2bf(b0.x) | ((u32)f2bf(b0.y) << 16);
            pv.y = (u32)f2bf(b0.z) | ((u32)f2bf(b0.w) << 16);
            pv.z = (u32)f2bf(b1.x) | ((u32)f2bf(b1.y) << 16);
            pv.w = (u32)f2bf(b1.z) | ((u32)f2bf(b1.w) << 16);
        }
        *(uint4*)&A[4] = pv;
    }
    f32x4 acc[4];
#pragma unroll
    for (int ct = 0; ct < 4; ++ct) acc[ct] = (f32x4){0.f, 0.f, 0.f, 0.f};
#pragma unroll
    for (int kc = 0; kc < 5; ++kc) {
#pragma unroll
        for (int ct = 0; ct < 4; ++ct) {
            bf16x8 b = *(const bf16x8*)&WS[(ct * 16 + lr) * 168 + kc * 32 + lq * 8];
            acc[ct] = MFMA(A[kc], b, acc[ct]);
        }
    }
#pragma unroll
    for (int ct = 0; ct < 4; ++ct)
#pragma unroll
        for (int r = 0; r < 4; ++r) {
            int row = w * 16 + lq * 4 + r;
            int col = ct * 16 + lr;
            eds[row * 64 + col] = f2bf(fmaxf(acc[ct][r], 0.f));
        }
    __syncthreads();
    for (int j = t; j < 4096; j += 512) {
        int le = j >> 5, wd = j & 31;
        int d = dstS[le];
        if (d < 0) continue;
        if (le > 0 && dstS[le - 1] == d) continue;  // not segment start
        float lo = 0.f, hi = 0.f;
        int le2 = le;
        do {
            u32 pair = *(const u32*)&eds[le2 * 64 + wd * 2];
            lo += bf2f((u16)(pair & 0xFFFFu));
            hi += bf2f((u16)(pair >> 16));
            ++le2;
        } while (le2 < 128 && dstS[le2] == d);
        bool bprev = (le == 0 && dprevS == d);
        bool bnext = (le2 == 128 && dnextS == d);
        u32* dw = (u32*)(outb + (long)d * 64 + wd * 2);
        if (bprev || bnext) {
            casAddPair(dw, lo, hi);
        } else {
            *dw = (u32)f2bf(lo) | ((u32)f2bf(hi) << 16);
        }
    }
}

// ---------------------------------------------------------------------------
// gather_g: half-wave (32 lanes, u32 channel pairs) per node; 8 nodes/block.
__global__ __launch_bounds__(256) void gather_g(
    const u16* __restrict__ m, const int* __restrict__ list,
    const u32* __restrict__ offc, u16* __restrict__ aggB,
    float* __restrict__ degOut, int N)
{
    int t = threadIdx.x;
    int hw = t >> 5, c = t & 31;
    long n = (long)blockIdx.x * 8 + hw;
    if (n >= N) return;
    u32 start = n ? offc[n - 1] : 0u;
    u32 end = offc[n];
    float s0 = 0.f, s1 = 0.f;
    for (u32 i = start; i < end; ++i) {
        int e = list[i];
        u32 pair = *(const u32*)&m[(long)e * 64 + c * 2];
        s0 += bf2f((u16)(pair & 0xFFFFu));
        s1 += bf2f((u16)(pair >> 16));
    }
    *(u32*)&aggB[n * 64 + c * 2] = (u32)f2bf(s0) | ((u32)f2bf(s1) << 16);
    if (degOut && c == 0) degOut[n] = (float)(end - start);
}

// ---------------------------------------------------------------------------
// lstm3: bidirectional JK-LSTM, weights register-resident, 64 nodes/tile,
// one tile per block. Swapped MFMA operands: acc = MFMA(Wh_frag, h_frag)
// puts 4 CONSECUTIVE hidden units (grow0..grow0+3) per thread per node,
// enabling packed b64 h-stores, float4 bias/Watt loads, and a fully
// in-register attention dot (no conflicted LDS re-reads).
// Gates pre-scaled by log2e (g-gate by 2*log2e) -> native v_exp_f32/rcp.
// Step 0 skips Whh (h==0, no hS zeroing); step 3 skips the h-store.
__global__ __launch_bounds__(512, 2) void lstm3(
    const u16* __restrict__ jkB, const u16* __restrict__ WhhB,
    const u16* __restrict__ WihB, const float* __restrict__ BS,
    const float* __restrict__ Watt, float* __restrict__ scores,
    int N)
{
    __shared__ u16 hS[64 * 136];         // h[node][128 hidden + 8 pad]  17408 B
    __shared__ u16 xS[4][64 * 72];       // x_t[node][64 + 8 pad], all steps 36864 B
    __shared__ float part[4 * 64 * 8];   // att partials [step][node][wave] 8192 B
    int t = threadIdx.x;
    int dir = blockIdx.y;
    int w = t >> 6, l = t & 63, lr = l & 15, lq = l >> 4;
    const u16* WhhD = WhhB + (long)dir * 65536;
    const u16* WihD = WihB + (long)dir * 32768;
    long n0 = (long)blockIdx.x * 64;

    // stage x for all 4 JK steps at once (64 nodes x 8 uint4 per step)
    {
        int n = t >> 3, j = t & 7;
        long gn = n0 + n;
#pragma unroll
        for (int k = 0; k < 4; ++k) {
            uint4 v = make_uint4(0, 0, 0, 0);
            if (gn < N) v = *(const uint4*)&jkB[((long)k * N + gn) * 64 + j * 8];
            *(uint4*)&xS[k][n * 72 + j * 8] = v;
        }
    }

    int grow0 = w * 16 + lq * 4;         // this thread's first hidden unit
    bf16x8 Wh[4][4], Wi[4][2];
    float4 b4[4];
#pragma unroll
    for (int ty = 0; ty < 4; ++ty) {
        int g = ty * 128 + w * 16 + lr;
#pragma unroll
        for (int kc = 0; kc < 4; ++kc)
            Wh[ty][kc] = *(const bf16x8*)&WhhD[g * 128 + kc * 32 + lq * 8];
#pragma unroll
        for (int kc = 0; kc < 2; ++kc)
            Wi[ty][kc] = *(const bf16x8*)&WihD[g * 64 + kc * 32 + lq * 8];
        b4[ty] = *(const float4*)&BS[dir * 512 + ty * 128 + grow0];
    }
    float4 Wa4 = *(const float4*)&Watt[dir * 128 + grow0];
    float* scOut = scores + (long)dir * N * 4;

    float creg[4][4] = {};
    __syncthreads();                     // xS visible

#pragma unroll 1
    for (int s = 0; s < 4; ++s) {
        int tt = dir ? (3 - s) : s;
        f32x4 acc[4][4];
#pragma unroll
        for (int ty = 0; ty < 4; ++ty) {
            f32x4 bv = {b4[ty].x, b4[ty].y, b4[ty].z, b4[ty].w};
#pragma unroll
            for (int nt = 0; nt < 4; ++nt) acc[ty][nt] = bv;
        }
        if (s) {                         // h==0 at step 0: skip Whh entirely
#pragma unroll
            for (int kc = 0; kc < 4; ++kc) {
                bf16x8 a[4];
#pragma unroll
                for (int nt = 0; nt < 4; ++nt)
                    a[nt] = *(const bf16x8*)&hS[(nt * 16 + lr) * 136 + kc * 32 + lq * 8];
#pragma unroll
                for (int ty = 0; ty < 4; ++ty)
#pragma unroll
                    for (int nt = 0; nt < 4; ++nt)
                        acc[ty][nt] = MFMA(Wh[ty][kc], a[nt], acc[ty][nt]);
            }
        }
#pragma unroll
        for (int kc = 0; kc < 2; ++kc) {
            bf16x8 a[4];
#pragma unroll
            for (int nt = 0; nt < 4; ++nt)
                a[nt] = *(const bf16x8*)&xS[tt][(nt * 16 + lr) * 72 + kc * 32 + lq * 8];
#pragma unroll
            for (int ty = 0; ty < 4; ++ty)
#pragma unroll
                for (int nt = 0; nt < 4; ++nt)
                    acc[ty][nt] = MFMA(Wi[ty][kc], a[nt], acc[ty][nt]);
        }
        if (s) __syncthreads();          // all hS reads done before overwrite
#pragma unroll
        for (int nt = 0; nt < 4; ++nt) {
            float hv[4];
#pragma unroll
            for (int r = 0; r < 4; ++r) {
                float iv = acc[0][nt][r], fv = acc[1][nt][r];
                float gv = acc[2][nt][r], ov = acc[3][nt][r];
                float c = creg[nt][r];
                float si = __builtin_amdgcn_rcpf(1.f + __builtin_amdgcn_exp2f(-iv));
                float sf = __builtin_amdgcn_rcpf(1.f + __builtin_amdgcn_exp2f(-fv));
                float tg = 2.f * __builtin_amdgcn_rcpf(1.f + __builtin_amdgcn_exp2f(-gv)) - 1.f;
                c = sf * c + si * tg;
                float so = __builtin_amdgcn_rcpf(1.f + __builtin_amdgcn_exp2f(-ov));
                float th = 2.f * __builtin_amdgcn_rcpf(
                               1.f + __builtin_amdgcn_exp2f(-2.8853900817779268f * c)) - 1.f;
                creg[nt][r] = c;
                hv[r] = so * th;
            }
            // attention partial over this thread's 4 hidden units (f32 h)
            float p = hv[0] * Wa4.x + hv[1] * Wa4.y + hv[2] * Wa4.z + hv[3] * Wa4.w;
            p += __shfl_xor(p, 16);
            p += __shfl_xor(p, 32);      // now sum over all lq -> wave's 16 units
            if (lq == 0) part[(tt * 64 + nt * 16 + lr) * 8 + w] = p;
            if (s < 3) {                 // h3 feeds nothing but attention
                u32 p0 = (u32)f2bf(hv[0]) | ((u32)f2bf(hv[1]) << 16);
                u32 p1 = (u32)f2bf(hv[2]) | ((u32)f2bf(hv[3]) << 16);
                *(uint2*)&hS[(nt * 16 + lr) * 136 + grow0] = make_uint2(p0, p1);
            }
        }
        if (s < 3) __syncthreads();      // new h visible
    }
    __syncthreads();                     // part visible
    if (t < 256) {
        int tt = t >> 6, node = t & 63;
        long gn = n0 + node;
        if (gn < N) {
            const float4* pp = (const float4*)&part[(tt * 64 + node) * 8];
            float4 a = pp[0], b = pp[1];
            scOut[gn * 4 + tt] = a.x + a.y + a.z + a.w + b.x + b.y + b.z + b.w;
        }
    }
}

// ---------------------------------------------------------------------------
__global__ __launch_bounds__(256) void final_kernel(
    const u16* __restrict__ jkB, const float* __restrict__ scores,
    const float* __restrict__ Wout, float* __restrict__ out, int N)
{
    __shared__ float feS[4][64];
    int t = threadIdx.x, l = t & 63, w = t >> 6;
    long n = (long)blockIdx.x * 4 + w;
    bool ok = (n < N);
    long nn = ok ? n : (long)(N - 1);
    float sc[4];
#pragma unroll
    for (int tt = 0; tt < 4; ++tt)
        sc[tt] = scores[nn * 4 + tt] + scores[(long)N * 4 + nn * 4 + tt];
    float m = fmaxf(fmaxf(sc[0], sc[1]), fmaxf(sc[2], sc[3]));
    float e0 = __expf(sc[0] - m), e1 = __expf(sc[1] - m);
    float e2 = __expf(sc[2] - m), e3 = __expf(sc[3] - m);
    float den = e0 + e1 + e2 + e3;
    float a0 = e0 / den, a1 = e1 / den, a2 = e2 / den, a3 = e3 / den;
    float fe = a0 * bf2f(jkB[nn * 64 + l]) + a1 * bf2f(jkB[((long)N + nn) * 64 + l]) +
               a2 * bf2f(jkB[((long)2 * N + nn) * 64 + l]) +
               a3 * bf2f(jkB[((long)3 * N + nn) * 64 + l]);
    feS[w][l] = fe;
    __syncthreads();
    float logit = 0.f;
    if (l < 40)
        for (int c = 0; c < 64; ++c) logit += feS[w][c] * Wout[l * 64 + c];
    float v = (l < 40) ? logit : -1e30f;
    for (int off = 32; off; off >>= 1) v = fmaxf(v, __shfl_xor(v, off));
    float ex = (l < 40) ? __expf(logit - v) : 0.f;
    for (int off = 32; off; off >>= 1) ex += __shfl_xor(ex, off);
    if (ok && l < 40) out[n * 40 + l] = logit - v - __logf(ex);
}

// ---------------------------------------------------------------------------
extern "C" void kernel_launch(void* const* d_in, const int* in_sizes, int n_in,
                              void* d_out, int out_size, void* d_ws, size_t ws_size,
                              hipStream_t stream)
{
    const float* x        = (const float*)d_in[0];
    const int*   eig      = (const int*)d_in[1];
    const float* eag      = (const float*)d_in[2];
    const int*   eilg     = (const int*)d_in[3];
    const float* ealg     = (const float*)d_in[4];
    const float* W_feat   = (const float*)d_in[5];
    const float* W_msg    = (const float*)d_in[6];
    const float* W_lg2g   = (const float*)d_in[7];
    const float* b_lg2g   = (const float*)d_in[8];
    const float* W_msg_l  = (const float*)d_in[9];
    const float* Wih_f    = (const float*)d_in[10];
    const float* Whh_f    = (const float*)d_in[11];
    const float* bih_f    = (const float*)d_in[12];
    const float* bhh_f    = (const float*)d_in[13];
    const float* Wih_b    = (const float*)d_in[14];
    const float* Whh_b    = (const float*)d_in[15];
    const float* bih_b    = (const float*)d_in[16];
    const float* bhh_b    = (const float*)d_in[17];
    const float* W_att    = (const float*)d_in[18];
    const float* W_out    = (const float*)d_in[20];

    int  N   = in_sizes[0] / 128;
    long Eg  = in_sizes[1] / 2;
    long Elg = in_sizes[3] / 2;

    char* wp = (char*)d_ws;
    auto alloc = [&](size_t bytes) -> char* {
        char* p = wp; wp += (bytes + 255) & ~(size_t)255; return p;
    };
    u16*   jkB    = (u16*)  alloc((size_t)4 * N * 64 * 2);
    u16*   mA     = (u16*)  alloc((size_t)Eg * 64 * 2);
    u16*   mB     = (u16*)  alloc((size_t)Eg * 64 * 2);
    u16*   aggB   = (u16*)  alloc((size_t)N * 64 * 2);
    float* deg    = (float*)alloc((size_t)N * 4);
    float* scores = (float*)alloc((size_t)2 * N * 4 * 4);
    u16*   WhhB   = (u16*)  alloc((size_t)2 * 65536 * 2);
    u16*   WihB   = (u16*)  alloc((size_t)2 * 32768 * 2);
    float* BS     = (float*)alloc((size_t)2 * 512 * 4);
    u32*   off_g  = (u32*)  alloc((size_t)(N + 1) * 4);
    int*   list_g = (int*)  alloc((size_t)Eg * 4);
    u32*   off_lg = (u32*)  alloc((size_t)(Eg + 1) * 4);
    int*   list_lg= (int*)  alloc((size_t)Elg * 4);
    u32*   part   = (u32*)  alloc((size_t)1024 * 4);

    prep_w<<<772, 256, 0, stream>>>(Whh_f, Whh_b, Wih_f, Wih_b,
                                    bih_f, bhh_f, bih_b, bhh_b, WhhB, WihB, BS);
    // ---- CSR build: g-graph (dst over nodes) ----
    hipMemsetAsync(off_g, 0, (size_t)(N + 1) * 4, stream);
    count_kernel<<<(int)((Eg + 255) / 256), 256, 0, stream>>>(eig + Eg, off_g, Eg);
    {
        int nb = (N + 1023) / 1024;
        scan1<<<nb, 256, 0, stream>>>(off_g, part, N);
        scan2<<<1, 1024, 0, stream>>>(part, nb, off_g + N);
        scan3<<<nb, 256, 0, stream>>>(off_g, part, N);
    }
    fill_kernel<<<(int)((Eg + 255) / 256), 256, 0, stream>>>(eig + Eg, off_g, list_g, Eg);
    // ---- CSR build: lg-graph (dst over g-edges) ----
    hipMemsetAsync(off_lg, 0, (size_t)(Eg + 1) * 4, stream);
    count_kernel<<<(int)((Elg + 255) / 256), 256, 0, stream>>>(eilg + Elg, off_lg, Elg);
    {
        int nb = (int)((Eg + 1023) / 1024);
        scan1<<<nb, 256, 0, stream>>>(off_lg, part, (int)Eg);
        scan2<<<1, 1024, 0, stream>>>(part, nb, off_lg + Eg);
        scan3<<<nb, 256, 0, stream>>>(off_lg, part, (int)Eg);
    }
    fill_kernel<<<(int)((Elg + 255) / 256), 256, 0, stream>>>(eilg + Elg, off_lg, list_lg, Elg);

    // jk0 = relu(x @ W_feat^T)
    rowgemm<128, true, false><<<(N + 63) / 64, 256, 0, stream>>>(
        x, W_feat, nullptr, nullptr, jkB, N);
    // initial msgs -> mA (plain stores)
    edge_msg_init2<<<(int)((Eg + 127) / 128), 512, 0, stream>>>(
        jkB, eig, eag, W_msg, mA, Eg);
    // jk1 = gather(mA) @ W_lg2g^T + deg*b
    gather_g<<<(N + 7) / 8, 256, 0, stream>>>(mA, list_g, off_g, aggB, deg, N);
    rowgemm<64, false, true><<<(N + 63) / 64, 256, 0, stream>>>(
        aggB, W_lg2g, b_lg2g, deg, jkB + (size_t)N * 64, N);
    // ---- linegraph layer 0: mA -> mB ----
    zero_fill<<<(int)((Eg * 8 + 255) / 256), 256, 0, stream>>>(off_lg, mB, Eg);
    edge_msg_lg2<<<(int)((Elg + 127) / 128), 512, 0, stream>>>(
        mA, eilg, ealg, W_msg_l, list_lg, mB, Elg);
    gather_g<<<(N + 7) / 8, 256, 0, stream>>>(mB, list_g, off_g, aggB, nullptr, N);
    rowgemm<64, false, true><<<(N + 63) / 64, 256, 0, stream>>>(
        aggB, W_lg2g, b_lg2g, nullptr, jkB + (size_t)2 * N * 64, N);
    // ---- linegraph layer 1: mB -> mA ----
    zero_fill<<<(int)((Eg * 8 + 255) / 256), 256, 0, stream>>>(off_lg, mA, Eg);
    edge_msg_lg2<<<(int)((Elg + 127) / 128), 512, 0, stream>>>(
        mB, eilg, ealg, W_msg_l + 64 * 144, list_lg, mA, Elg);
    gather_g<<<(N + 7) / 8, 256, 0, stream>>>(mA, list_g, off_g, aggB, nullptr, N);
    rowgemm<64, false, true><<<(N + 63) / 64, 256, 0, stream>>>(
        aggB, W_lg2g, b_lg2g, nullptr, jkB + (size_t)3 * N * 64, N);
    // ---- JK bidirectional LSTM (one 64-node tile per block) ----
    {
        int ntiles = (N + 63) / 64;
        lstm3<<<dim3(ntiles, 2), 512, 0, stream>>>(
            jkB, WhhB, WihB, BS, W_att, scores, N);
    }
    final_kernel<<<(N + 3) / 4, 256, 0, stream>>>(
        jkB, scores, W_out, (float*)d_out, N);
}

// Round 2
// 1060.961 us; speedup vs baseline: 1.0707x; 1.0397x over previous
//
#include <hip/hip_runtime.h>

typedef unsigned short u16;
typedef unsigned int u32;
typedef __attribute__((ext_vector_type(8))) short bf16x8;
typedef __attribute__((ext_vector_type(4))) float f32x4;

#define MFMA(a, b, c) __builtin_amdgcn_mfma_f32_16x16x32_bf16(a, b, c, 0, 0, 0)

__device__ __forceinline__ u16 f2bf(float x) {
    union { float f; u32 u; } v; v.f = x;
    u32 r = (v.u + 0x7FFFu + ((v.u >> 16) & 1u)) >> 16;
    return (u16)r;
}
__device__ __forceinline__ float bf2f(u16 b) {
    union { u32 u; float f; } v; v.u = ((u32)b) << 16;
    return v.f;
}
__device__ __forceinline__ void casAddPair(u32* w, float lo, float hi) {
    u32 old = *w, assumed;
    do {
        assumed = old;
        u32 des = (u32)f2bf(bf2f((u16)(assumed & 0xFFFFu)) + lo) |
                  ((u32)f2bf(bf2f((u16)(assumed >> 16)) + hi) << 16);
        if (des == assumed) break;
        old = atomicCAS(w, assumed, des);
    } while (old != assumed);
}

// ---------------------------------------------------------------------------
// prep: convert LSTM weights to bf16, combine biases.
// Pre-scale by log2(e) (g-gate rows by 2*log2(e)) so lstm3 can use native
// v_exp_f32 (2^x) with free negation modifiers.
__global__ __launch_bounds__(256) void prep_w(
    const float* __restrict__ Whh_f, const float* __restrict__ Whh_b,
    const float* __restrict__ Wih_f, const float* __restrict__ Wih_b,
    const float* __restrict__ bih_f, const float* __restrict__ bhh_f,
    const float* __restrict__ bih_b, const float* __restrict__ bhh_b,
    u16* __restrict__ WhhB, u16* __restrict__ WihB, float* __restrict__ BS)
{
    const float L2E = 1.4426950408889634f;
    int i = blockIdx.x * 256 + threadIdx.x;
    if (i < 131072) {
        int d = i >> 16, r = i & 65535;
        float s = (((r >> 14) & 3) == 2) ? 2.f * L2E : L2E;   // gate row = r>>7, gate = row>>7
        WhhB[i] = f2bf(s * (d ? Whh_b[r] : Whh_f[r]));
    } else if (i < 196608) {
        int i2 = i - 131072; int d = i2 >> 15, r = i2 & 32767;
        float s = (((r >> 13) & 3) == 2) ? 2.f * L2E : L2E;
        WihB[i2] = f2bf(s * (d ? Wih_b[r] : Wih_f[r]));
    } else if (i < 197632) {
        int i3 = i - 196608; int d = i3 >> 9, g = i3 & 511;
        float s = (((g >> 7) & 3) == 2) ? 2.f * L2E : L2E;
        BS[i3] = s * (d ? (bih_b[g] + bhh_b[g]) : (bih_f[g] + bhh_f[g]));
    }
}

// ---------------------------------------------------------------------------
// CSR build
__global__ __launch_bounds__(256) void count_kernel(const int* __restrict__ dst,
                                                    u32* __restrict__ cnt, long E)
{
    long i = (long)blockIdx.x * 256 + threadIdx.x;
    if (i < E) atomicAdd(&cnt[dst[i]], 1u);
}

__global__ __launch_bounds__(256) void scan1(const u32* __restrict__ a,
                                             u32* __restrict__ part, int n)
{
    __shared__ u32 ts[256];
    int b = blockIdx.x, t = threadIdx.x;
    long i0 = (long)b * 1024 + t * 4;
    u32 s = 0;
#pragma unroll
    for (int k = 0; k < 4; ++k) { long i = i0 + k; if (i < n) s += a[i]; }
    ts[t] = s; __syncthreads();
    for (int off = 1; off < 256; off <<= 1) {
        u32 x = (t >= off) ? ts[t - off] : 0u;
        __syncthreads(); ts[t] += x; __syncthreads();
    }
    if (t == 255) part[b] = ts[255];
}

__global__ __launch_bounds__(1024) void scan2(u32* __restrict__ part, int nb,
                                              u32* __restrict__ total_out)
{
    __shared__ u32 ts[1024];
    int t = threadIdx.x;
    u32 v = (t < nb) ? part[t] : 0u;
    ts[t] = v; __syncthreads();
    for (int off = 1; off < 1024; off <<= 1) {
        u32 x = (t >= off) ? ts[t - off] : 0u;
        __syncthreads(); ts[t] += x; __syncthreads();
    }
    if (t < nb) part[t] = ts[t] - v;
    if (t == 1023 && total_out) *total_out = ts[1023];
}

__global__ __launch_bounds__(256) void scan3(u32* __restrict__ a,
                                             const u32* __restrict__ part, int n)
{
    __shared__ u32 ts[256];
    int b = blockIdx.x, t = threadIdx.x;
    long i0 = (long)b * 1024 + t * 4;
    u32 v[4]; u32 s = 0;
#pragma unroll
    for (int k = 0; k < 4; ++k) { long i = i0 + k; v[k] = (i < n) ? a[i] : 0u; s += v[k]; }
    ts[t] = s; __syncthreads();
    for (int off = 1; off < 256; off <<= 1) {
        u32 x = (t >= off) ? ts[t - off] : 0u;
        __syncthreads(); ts[t] += x; __syncthreads();
    }
    u32 run = part[b] + ts[t] - s;
#pragma unroll
    for (int k = 0; k < 4; ++k) {
        long i = i0 + k;
        if (i < n) { u32 x = v[k]; a[i] = run; run += x; }
    }
}

__global__ __launch_bounds__(256) void fill_kernel(const int* __restrict__ dst,
                                                   u32* __restrict__ off,
                                                   int* __restrict__ list, long E)
{
    long i = (long)blockIdx.x * 256 + threadIdx.x;
    if (i < E) {
        u32 pos = atomicAdd(&off[dst[i]], 1u);
        list[pos] = (int)i;
    }
}

// ---------------------------------------------------------------------------
// zero_fill: zero only rows needing init (empty buckets + buckets crossing a
// 128-position block boundary, which are CAS-accumulated).
__global__ __launch_bounds__(256) void zero_fill(const u32* __restrict__ offc,
                                                 u16* __restrict__ outb, long NB)
{
    long idx = (long)blockIdx.x * 256 + threadIdx.x;
    long n = idx >> 3; int q = (int)(idx & 7);
    if (n >= NB) return;
    u32 s = n ? offc[n - 1] : 0u;
    u32 e = offc[n];
    bool need = (s == e) || ((s >> 7) != ((e - 1) >> 7));
    if (need) *(uint4*)(outb + n * 64 + q * 8) = make_uint4(0, 0, 0, 0);
}

// ---------------------------------------------------------------------------
// rowgemm: outb[M x 64] (bf16) = act(in[M x K] @ W[64 x K]^T (+ bias*scale))
template <int K, bool RELU, bool INBF16>
__global__ __launch_bounds__(256) void rowgemm(
    const void* __restrict__ in, const float* __restrict__ W,
    const float* __restrict__ bias, const float* __restrict__ bias_scale,
    u16* __restrict__ outb, int M)
{
    constexpr int KP = K + 8;
    __shared__ u16 inS[64 * KP];
    __shared__ u16 WS[64 * KP];
    int t = threadIdx.x;
    long rb = (long)blockIdx.x * 64;
    for (int i = t; i < 64 * K; i += 256) {
        int c = i / K, k = i - c * K;
        WS[c * KP + k] = f2bf(W[i]);
    }
    if (INBF16) {
        const u16* inb = (const u16*)in;
        for (int i = t; i < 64 * K / 8; i += 256) {
            int r = i / (K / 8), q = i - r * (K / 8);
            long gr = rb + r;
            uint4 v = make_uint4(0, 0, 0, 0);
            if (gr < M) v = *(const uint4*)&inb[gr * (long)K + q * 8];
            *(uint4*)&inS[r * KP + q * 8] = v;
        }
    } else {
        const float* inf = (const float*)in;
        for (int i = t; i < 64 * K; i += 256) {
            int r = i / K, k = i - r * K;
            long gr = rb + r;
            inS[r * KP + k] = (gr < M) ? f2bf(inf[gr * (long)K + k]) : (u16)0;
        }
    }
    __syncthreads();
    int l = t & 63, w = t >> 6, lr = l & 15, lq = l >> 4;
    f32x4 acc[4];
#pragma unroll
    for (int i = 0; i < 4; ++i) acc[i] = (f32x4){0.f, 0.f, 0.f, 0.f};
#pragma unroll
    for (int kc = 0; kc < K; kc += 32) {
        bf16x8 a = *(const bf16x8*)&inS[(w * 16 + lr) * KP + kc + lq * 8];
#pragma unroll
        for (int ct = 0; ct < 4; ++ct) {
            bf16x8 b = *(const bf16x8*)&WS[(ct * 16 + lr) * KP + kc + lq * 8];
            acc[ct] = MFMA(a, b, acc[ct]);
        }
    }
#pragma unroll
    for (int ct = 0; ct < 4; ++ct)
#pragma unroll
        for (int r = 0; r < 4; ++r) {
            long gr = rb + w * 16 + lq * 4 + r;
            if (gr < M) {
                int c = ct * 16 + lr;
                float v = acc[ct][r];
                if (bias) v += bias[c] * (bias_scale ? bias_scale[gr] : 1.f);
                if (RELU) v = fmaxf(v, 0.f);
                outb[gr * 64 + c] = f2bf(v);
            }
        }
}

// ---------------------------------------------------------------------------
// edge_msg_init2: direct-gather A-fragments (no inS staging).
__global__ __launch_bounds__(512, 4) void edge_msg_init2(
    const u16* __restrict__ feat, const int* __restrict__ ei,
    const float* __restrict__ attr, const float* __restrict__ W,
    u16* __restrict__ outb, long E)
{
    __shared__ u16 WS[64 * 168];
    __shared__ u16 eds[128 * 64];
    int t = threadIdx.x;
    long eb = (long)blockIdx.x * 128;
    for (int i = t; i < 64 * 144; i += 512) {
        int c = i / 144, k = i - c * 144;
        WS[c * 168 + k] = f2bf(W[i]);
    }
    for (int i = t; i < 64 * 24; i += 512) {
        int c = i / 24, k = 144 + (i - c * 24);
        WS[c * 168 + k] = 0;
    }
    int w = t >> 6, l = t & 63, lr = l & 15, lq = l >> 4;
    long e = eb + w * 16 + lr;
    long ec = (e < E) ? e : (E - 1);
    int src = ei[ec], dst = ei[E + ec];
    bf16x8 A[5];
    {
        const uint4* sp = (const uint4*)(feat + (long)src * 64);
        const uint4* dp = (const uint4*)(feat + (long)dst * 64);
        *(uint4*)&A[0] = sp[lq];
        *(uint4*)&A[1] = sp[4 + lq];
        *(uint4*)&A[2] = dp[lq];
        *(uint4*)&A[3] = dp[4 + lq];
        uint4 pv = make_uint4(0, 0, 0, 0);
        if (lq < 2) {
            const float4* ap = (const float4*)(attr + ec * 16) + lq * 2;
            float4 b0 = ap[0], b1 = ap[1];
            pv.x = (u32)f2bf(b0.x) | ((u32)f2bf(b0.y) << 16);
            pv.y = (u32)f2bf(b0.z) | ((u32)f2bf(b0.w) << 16);
            pv.z = (u32)f2bf(b1.x) | ((u32)f2bf(b1.y) << 16);
            pv.w = (u32)f2bf(b1.z) | ((u32)f2bf(b1.w) << 16);
        }
        *(uint4*)&A[4] = pv;
    }
    __syncthreads();
    f32x4 acc[4];
#pragma unroll
    for (int ct = 0; ct < 4; ++ct) acc[ct] = (f32x4){0.f, 0.f, 0.f, 0.f};
#pragma unroll
    for (int kc = 0; kc < 5; ++kc) {
#pragma unroll
        for (int ct = 0; ct < 4; ++ct) {
            bf16x8 b = *(const bf16x8*)&WS[(ct * 16 + lr) * 168 + kc * 32 + lq * 8];
            acc[ct] = MFMA(A[kc], b, acc[ct]);
        }
    }
#pragma unroll
    for (int ct = 0; ct < 4; ++ct)
#pragma unroll
        for (int r = 0; r < 4; ++r) {
            int row = w * 16 + lq * 4 + r;
            int col = ct * 16 + lr;
            eds[row * 64 + col] = f2bf(fmaxf(acc[ct][r], 0.f));
        }
    __syncthreads();
    for (int j = t; j < 1024; j += 512) {
        int le = j >> 3, q = j & 7;
        long e2 = eb + le;
        if (e2 < E)
            *(uint4*)(outb + e2 * 64 + q * 8) = *(const uint4*)&eds[le * 64 + q * 8];
    }
}

// ---------------------------------------------------------------------------
// edge_msg_lg2: direct-gather A-frags, dst-sorted (CSR) order, segmented
// reduction epilogue (plain store for intra-block segments, CAS at borders).
__global__ __launch_bounds__(512, 4) void edge_msg_lg2(
    const u16* __restrict__ feat, const int* __restrict__ ei,
    const float* __restrict__ attr, const float* __restrict__ W,
    const int* __restrict__ list, u16* __restrict__ outb, long E)
{
    __shared__ u16 WS[64 * 168];
    __shared__ u16 eds[128 * 64];
    __shared__ int dstS[128];
    __shared__ int idS[128];
    __shared__ int srcS[128];
    __shared__ int dprevS, dnextS;
    int t = threadIdx.x;
    long pb = (long)blockIdx.x * 128;
    for (int i = t; i < 64 * 144; i += 512) {
        int c = i / 144, k = i - c * 144;
        WS[c * 168 + k] = f2bf(W[i]);
    }
    for (int i = t; i < 64 * 24; i += 512) {
        int c = i / 24, k = 144 + (i - c * 24);
        WS[c * 168 + k] = 0;
    }
    if (t < 128) {
        long p = pb + t;
        int id = (p < E) ? list[p] : -1;
        idS[t] = id;
        srcS[t] = (id >= 0) ? ei[id] : 0;
        dstS[t] = (id >= 0) ? ei[E + id] : -1;
    } else if (t == 128) {
        dprevS = (pb > 0) ? ei[E + list[pb - 1]] : -2;
    } else if (t == 129) {
        dnextS = (pb + 128 < E) ? ei[E + list[pb + 128]] : -2;
    }
    __syncthreads();
    int w = t >> 6, l = t & 63, lr = l & 15, lq = l >> 4;
    int el = w * 16 + lr;
    int id = idS[el];
    long idc = (id >= 0) ? (long)id : 0;
    int src = srcS[el];
    int dst = (dstS[el] >= 0) ? dstS[el] : 0;
    bf16x8 A[5];
    {
        const uint4* sp = (const uint4*)(feat + (long)src * 64);
        const uint4* dp = (const uint4*)(feat + (long)dst * 64);
        *(uint4*)&A[0] = sp[lq];
        *(uint4*)&A[1] = sp[4 + lq];
        *(uint4*)&A[2] = dp[lq];
        *(uint4*)&A[3] = dp[4 + lq];
        uint4 pv = make_uint4(0, 0, 0, 0);
        if (lq < 2) {
            const float4* ap = (const float4*)(attr + idc * 16) + lq * 2;
            float4 b0 = ap[0], b1 = ap[1];
            pv.x = (u32)f2bf(b0.x) | ((u32)f2bf(b0.y) << 16);
            pv.y = (u32)f2bf(b0.z) | ((u32)f2bf(b0.w) << 16);
            pv.z = (u32)f2bf(b1.x) | ((u32)f2bf(b1.y) << 16);
            pv.w = (u32)f2bf(b1.z) | ((u32)f2bf(b1.w) << 16);
        }
        *(uint4*)&A[4] = pv;
    }
    f32x4 acc[4];
#pragma unroll
    for (int ct = 0; ct < 4; ++ct) acc[ct] = (f32x4){0.f, 0.f, 0.f, 0.f};
#pragma unroll
    for (int kc = 0; kc < 5; ++kc) {
#pragma unroll
        for (int ct = 0; ct < 4; ++ct) {
            bf16x8 b = *(const bf16x8*)&WS[(ct * 16 + lr) * 168 + kc * 32 + lq * 8];
            acc[ct] = MFMA(A[kc], b, acc[ct]);
        }
    }
#pragma unroll
    for (int ct = 0; ct < 4; ++ct)
#pragma unroll
        for (int r = 0; r < 4; ++r) {
            int row = w * 16 + lq * 4 + r;
            int col = ct * 16 + lr;
            eds[row * 64 + col] = f2bf(fmaxf(acc[ct][r], 0.f));
        }
    __syncthreads();
    for (int j = t; j < 4096; j += 512) {
        int le = j >> 5, wd = j & 31;
        int d = dstS[le];
        if (d < 0) continue;
        if (le > 0 && dstS[le - 1] == d) continue;  // not segment start
        float lo = 0.f, hi = 0.f;
        int le2 = le;
        do {
            u32 pair = *(const u32*)&eds[le2 * 64 + wd * 2];
            lo += bf2f((u16)(pair & 0xFFFFu));
            hi += bf2f((u16)(pair >> 16));
            ++le2;
        } while (le2 < 128 && dstS[le2] == d);
        bool bprev = (le == 0 && dprevS == d);
        bool bnext = (le2 == 128 && dnextS == d);
        u32* dw = (u32*)(outb + (long)d * 64 + wd * 2);
        if (bprev || bnext) {
            casAddPair(dw, lo, hi);
        } else {
            *dw = (u32)f2bf(lo) | ((u32)f2bf(hi) << 16);
        }
    }
}

// ---------------------------------------------------------------------------
// gather_g: half-wave (32 lanes, u32 channel pairs) per node; 8 nodes/block.
__global__ __launch_bounds__(256) void gather_g(
    const u16* __restrict__ m, const int* __restrict__ list,
    const u32* __restrict__ offc, u16* __restrict__ aggB,
    float* __restrict__ degOut, int N)
{
    int t = threadIdx.x;
    int hw = t >> 5, c = t & 31;
    long n = (long)blockIdx.x * 8 + hw;
    if (n >= N) return;
    u32 start = n ? offc[n - 1] : 0u;
    u32 end = offc[n];
    float s0 = 0.f, s1 = 0.f;
    for (u32 i = start; i < end; ++i) {
        int e = list[i];
        u32 pair = *(const u32*)&m[(long)e * 64 + c * 2];
        s0 += bf2f((u16)(pair & 0xFFFFu));
        s1 += bf2f((u16)(pair >> 16));
    }
    *(u32*)&aggB[n * 64 + c * 2] = (u32)f2bf(s0) | ((u32)f2bf(s1) << 16);
    if (degOut && c == 0) degOut[n] = (float)(end - start);
}

// ---------------------------------------------------------------------------
// lstm3: bidirectional JK-LSTM, 64 nodes/tile, one tile per block.
// Register-pressure-structured (r1 spilled ~32 regs -> 97 MB scratch writes):
//  - Wh (4x4 frags, 64 VGPR) register-resident (used 3 steps x 16 MFMAs).
//  - Wi + bias moved to LDS (frees 48 VGPR; Wih is L2-resident, staged once).
//  - Gates split into 2 passes: A = (i,g) -> u = sig(i)*tanh(g);
//    B = (f,o) -> c = sig(f)*c + u, h = sig(o)*tanh(c). acc[2][4] = 32 VGPR.
// Peak live ~170 regs: fits the 256 cap of __launch_bounds__(512,2), no spill.
// LDS 138 KB -> 1 block/CU (occupancy will read low; that is expected).
__global__ __launch_bounds__(512, 2) void lstm3(
    const u16* __restrict__ jkB, const u16* __restrict__ WhhB,
    const u16* __restrict__ WihB, const float* __restrict__ BS,
    const float* __restrict__ Watt, float* __restrict__ scores,
    int N)
{
    __shared__ u16 hS[64 * 136];         // 17408 B
    __shared__ u16 xS[4][64 * 72];       // 36864 B
    __shared__ u16 WiS[512 * 72];        // 73728 B (padded stride 72)
    __shared__ float bsS[512];           //  2048 B
    __shared__ float part[4 * 64 * 8];   //  8192 B   total 138240 B
    int t = threadIdx.x;
    int dir = blockIdx.y;
    int w = t >> 6, l = t & 63, lr = l & 15, lq = l >> 4;
    const u16* WhhD = WhhB + (long)dir * 65536;
    const u16* WihD = WihB + (long)dir * 32768;
    long n0 = (long)blockIdx.x * 64;

    // stage x for all 4 JK steps (64 nodes x 8 uint4 per step)
    {
        int n = t >> 3, j = t & 7;
        long gn = n0 + n;
#pragma unroll
        for (int k = 0; k < 4; ++k) {
            uint4 v = make_uint4(0, 0, 0, 0);
            if (gn < N) v = *(const uint4*)&jkB[((long)k * N + gn) * 64 + j * 8];
            *(uint4*)&xS[k][n * 72 + j * 8] = v;
        }
    }
    // stage Wi (512 gate-rows x 64, padded to 72) and bias
#pragma unroll
    for (int i = t; i < 4096; i += 512) {
        int g = i >> 3, q = i & 7;
        *(uint4*)&WiS[g * 72 + q * 8] = *(const uint4*)&WihD[g * 64 + q * 8];
    }
    bsS[t] = BS[dir * 512 + t];

    int grow0 = w * 16 + lq * 4;         // this thread's first hidden unit
    bf16x8 Wh[4][4];
#pragma unroll
    for (int ty = 0; ty < 4; ++ty) {
        int g = ty * 128 + w * 16 + lr;
#pragma unroll
        for (int kc = 0; kc < 4; ++kc)
            Wh[ty][kc] = *(const bf16x8*)&WhhD[g * 128 + kc * 32 + lq * 8];
    }
    float4 Wa4 = *(const float4*)&Watt[dir * 128 + grow0];
    float* scOut = scores + (long)dir * N * 4;

    float creg[4][4] = {};
    __syncthreads();                     // xS / WiS / bsS visible

#pragma unroll 1
    for (int s = 0; s < 4; ++s) {
        int tt = dir ? (3 - s) : s;
        float u[4][4];
        // ---------------- pass A: gates i (0) and g (2) -> u ----------------
        {
            f32x4 acc[2][4];
            f32x4 bi = *(const f32x4*)&bsS[grow0];
            f32x4 bg = *(const f32x4*)&bsS[256 + grow0];
#pragma unroll
            for (int nt = 0; nt < 4; ++nt) { acc[0][nt] = bi; acc[1][nt] = bg; }
            if (s) {
#pragma unroll
                for (int kc = 0; kc < 4; ++kc) {
                    bf16x8 a[4];
#pragma unroll
                    for (int nt = 0; nt < 4; ++nt)
                        a[nt] = *(const bf16x8*)&hS[(nt * 16 + lr) * 136 + kc * 32 + lq * 8];
#pragma unroll
                    for (int nt = 0; nt < 4; ++nt) {
                        acc[0][nt] = MFMA(Wh[0][kc], a[nt], acc[0][nt]);
                        acc[1][nt] = MFMA(Wh[2][kc], a[nt], acc[1][nt]);
                    }
                }
            }
#pragma unroll
            for (int kc = 0; kc < 2; ++kc) {
                bf16x8 wi = *(const bf16x8*)&WiS[(w * 16 + lr) * 72 + kc * 32 + lq * 8];
                bf16x8 wg = *(const bf16x8*)&WiS[(256 + w * 16 + lr) * 72 + kc * 32 + lq * 8];
                bf16x8 a[4];
#pragma unroll
                for (int nt = 0; nt < 4; ++nt)
                    a[nt] = *(const bf16x8*)&xS[tt][(nt * 16 + lr) * 72 + kc * 32 + lq * 8];
#pragma unroll
                for (int nt = 0; nt < 4; ++nt) {
                    acc[0][nt] = MFMA(wi, a[nt], acc[0][nt]);
                    acc[1][nt] = MFMA(wg, a[nt], acc[1][nt]);
                }
            }
#pragma unroll
            for (int nt = 0; nt < 4; ++nt)
#pragma unroll
                for (int r = 0; r < 4; ++r) {
                    float si = __builtin_amdgcn_rcpf(
                        1.f + __builtin_amdgcn_exp2f(-acc[0][nt][r]));
                    float tg = 2.f * __builtin_amdgcn_rcpf(
                        1.f + __builtin_amdgcn_exp2f(-acc[1][nt][r])) - 1.f;
                    u[nt][r] = si * tg;
                }
        }
        // ---------------- pass B: gates f (1) and o (3) -> c, h -------------
        {
            f32x4 acc[2][4];
            f32x4 bf = *(const f32x4*)&bsS[128 + grow0];
            f32x4 bo = *(const f32x4*)&bsS[384 + grow0];
#pragma unroll
            for (int nt = 0; nt < 4; ++nt) { acc[0][nt] = bf; acc[1][nt] = bo; }
            if (s) {
#pragma unroll
                for (int kc = 0; kc < 4; ++kc) {
                    bf16x8 a[4];
#pragma unroll
                    for (int nt = 0; nt < 4; ++nt)
                        a[nt] = *(const bf16x8*)&hS[(nt * 16 + lr) * 136 + kc * 32 + lq * 8];
#pragma unroll
                    for (int nt = 0; nt < 4; ++nt) {
                        acc[0][nt] = MFMA(Wh[1][kc], a[nt], acc[0][nt]);
                        acc[1][nt] = MFMA(Wh[3][kc], a[nt], acc[1][nt]);
                    }
                }
            }
#pragma unroll
            for (int kc = 0; kc < 2; ++kc) {
                bf16x8 wf = *(const bf16x8*)&WiS[(128 + w * 16 + lr) * 72 + kc * 32 + lq * 8];
                bf16x8 wo = *(const bf16x8*)&WiS[(384 + w * 16 + lr) * 72 + kc * 32 + lq * 8];
                bf16x8 a[4];
#pragma unroll
                for (int nt = 0; nt < 4; ++nt)
                    a[nt] = *(const bf16x8*)&xS[tt][(nt * 16 + lr) * 72 + kc * 32 + lq * 8];
#pragma unroll
                for (int nt = 0; nt < 4; ++nt) {
                    acc[0][nt] = MFMA(wf, a[nt], acc[0][nt]);
                    acc[1][nt] = MFMA(wo, a[nt], acc[1][nt]);
                }
            }
            if (s) __syncthreads();      // all hS reads (A+B) done before overwrite
#pragma unroll
            for (int nt = 0; nt < 4; ++nt) {
                float hv[4];
#pragma unroll
                for (int r = 0; r < 4; ++r) {
                    float sf = __builtin_amdgcn_rcpf(
                        1.f + __builtin_amdgcn_exp2f(-acc[0][nt][r]));
                    float c = sf * creg[nt][r] + u[nt][r];
                    float so = __builtin_amdgcn_rcpf(
                        1.f + __builtin_amdgcn_exp2f(-acc[1][nt][r]));
                    float th = 2.f * __builtin_amdgcn_rcpf(
                        1.f + __builtin_amdgcn_exp2f(-2.8853900817779268f * c)) - 1.f;
                    creg[nt][r] = c;
                    hv[r] = so * th;
                }
                // attention partial over this thread's 4 hidden units (f32 h)
                float p = hv[0] * Wa4.x + hv[1] * Wa4.y + hv[2] * Wa4.z + hv[3] * Wa4.w;
                p += __shfl_xor(p, 16);
                p += __shfl_xor(p, 32);  // sum over lq -> wave's 16 units
                if (lq == 0) part[(tt * 64 + nt * 16 + lr) * 8 + w] = p;
                if (s < 3) {             // h3 feeds nothing but attention
                    u32 p0 = (u32)f2bf(hv[0]) | ((u32)f2bf(hv[1]) << 16);
                    u32 p1 = (u32)f2bf(hv[2]) | ((u32)f2bf(hv[3]) << 16);
                    *(uint2*)&hS[(nt * 16 + lr) * 136 + grow0] = make_uint2(p0, p1);
                }
            }
        }
        if (s < 3) __syncthreads();      // new h visible
    }
    __syncthreads();                     // part visible
    if (t < 256) {
        int tt = t >> 6, node = t & 63;
        long gn = n0 + node;
        if (gn < N) {
            const float4* pp = (const float4*)&part[(tt * 64 + node) * 8];
            float4 a = pp[0], b = pp[1];
            scOut[gn * 4 + tt] = a.x + a.y + a.z + a.w + b.x + b.y + b.z + b.w;
        }
    }
}

// ---------------------------------------------------------------------------
__global__ __launch_bounds__(256) void final_kernel(
    const u16* __restrict__ jkB, const float* __restrict__ scores,
    const float* __restrict__ Wout, float* __restrict__ out, int N)
{
    __shared__ float feS[4][64];
    int t = threadIdx.x, l = t & 63, w = t >> 6;
    long n = (long)blockIdx.x * 4 + w;
    bool ok = (n < N);
    long nn = ok ? n : (long)(N - 1);
    float sc[4];
#pragma unroll
    for (int tt = 0; tt < 4; ++tt)
        sc[tt] = scores[nn * 4 + tt] + scores[(long)N * 4 + nn * 4 + tt];
    float m = fmaxf(fmaxf(sc[0], sc[1]), fmaxf(sc[2], sc[3]));
    float e0 = __expf(sc[0] - m), e1 = __expf(sc[1] - m);
    float e2 = __expf(sc[2] - m), e3 = __expf(sc[3] - m);
    float den = e0 + e1 + e2 + e3;
    float a0 = e0 / den, a1 = e1 / den, a2 = e2 / den, a3 = e3 / den;
    float fe = a0 * bf2f(jkB[nn * 64 + l]) + a1 * bf2f(jkB[((long)N + nn) * 64 + l]) +
               a2 * bf2f(jkB[((long)2 * N + nn) * 64 + l]) +
               a3 * bf2f(jkB[((long)3 * N + nn) * 64 + l]);
    feS[w][l] = fe;
    __syncthreads();
    float logit = 0.f;
    if (l < 40)
        for (int c = 0; c < 64; ++c) logit += feS[w][c] * Wout[l * 64 + c];
    float v = (l < 40) ? logit : -1e30f;
    for (int off = 32; off; off >>= 1) v = fmaxf(v, __shfl_xor(v, off));
    float ex = (l < 40) ? __expf(logit - v) : 0.f;
    for (int off = 32; off; off >>= 1) ex += __shfl_xor(ex, off);
    if (ok && l < 40) out[n * 40 + l] = logit - v - __logf(ex);
}

// ---------------------------------------------------------------------------
extern "C" void kernel_launch(void* const* d_in, const int* in_sizes, int n_in,
                              void* d_out, int out_size, void* d_ws, size_t ws_size,
                              hipStream_t stream)
{
    const float* x        = (const float*)d_in[0];
    const int*   eig      = (const int*)d_in[1];
    const float* eag      = (const float*)d_in[2];
    const int*   eilg     = (const int*)d_in[3];
    const float* ealg     = (const float*)d_in[4];
    const float* W_feat   = (const float*)d_in[5];
    const float* W_msg    = (const float*)d_in[6];
    const float* W_lg2g   = (const float*)d_in[7];
    const float* b_lg2g   = (const float*)d_in[8];
    const float* W_msg_l  = (const float*)d_in[9];
    const float* Wih_f    = (const float*)d_in[10];
    const float* Whh_f    = (const float*)d_in[11];
    const float* bih_f    = (const float*)d_in[12];
    const float* bhh_f    = (const float*)d_in[13];
    const float* Wih_b    = (const float*)d_in[14];
    const float* Whh_b    = (const float*)d_in[15];
    const float* bih_b    = (const float*)d_in[16];
    const float* bhh_b    = (const float*)d_in[17];
    const float* W_att    = (const float*)d_in[18];
    const float* W_out    = (const float*)d_in[20];

    int  N   = in_sizes[0] / 128;
    long Eg  = in_sizes[1] / 2;
    long Elg = in_sizes[3] / 2;

    char* wp = (char*)d_ws;
    auto alloc = [&](size_t bytes) -> char* {
        char* p = wp; wp += (bytes + 255) & ~(size_t)255; return p;
    };
    u16*   jkB    = (u16*)  alloc((size_t)4 * N * 64 * 2);
    u16*   mA     = (u16*)  alloc((size_t)Eg * 64 * 2);
    u16*   mB     = (u16*)  alloc((size_t)Eg * 64 * 2);
    u16*   aggB   = (u16*)  alloc((size_t)N * 64 * 2);
    float* deg    = (float*)alloc((size_t)N * 4);
    float* scores = (float*)alloc((size_t)2 * N * 4 * 4);
    u16*   WhhB   = (u16*)  alloc((size_t)2 * 65536 * 2);
    u16*   WihB   = (u16*)  alloc((size_t)2 * 32768 * 2);
    float* BS     = (float*)alloc((size_t)2 * 512 * 4);
    u32*   off_g  = (u32*)  alloc((size_t)(N + 1) * 4);
    int*   list_g = (int*)  alloc((size_t)Eg * 4);
    u32*   off_lg = (u32*)  alloc((size_t)(Eg + 1) * 4);
    int*   list_lg= (int*)  alloc((size_t)Elg * 4);
    u32*   part   = (u32*)  alloc((size_t)1024 * 4);

    prep_w<<<772, 256, 0, stream>>>(Whh_f, Whh_b, Wih_f, Wih_b,
                                    bih_f, bhh_f, bih_b, bhh_b, WhhB, WihB, BS);
    // ---- CSR build: g-graph (dst over nodes) ----
    hipMemsetAsync(off_g, 0, (size_t)(N + 1) * 4, stream);
    count_kernel<<<(int)((Eg + 255) / 256), 256, 0, stream>>>(eig + Eg, off_g, Eg);
    {
        int nb = (N + 1023) / 1024;
        scan1<<<nb, 256, 0, stream>>>(off_g, part, N);
        scan2<<<1, 1024, 0, stream>>>(part, nb, off_g + N);
        scan3<<<nb, 256, 0, stream>>>(off_g, part, N);
    }
    fill_kernel<<<(int)((Eg + 255) / 256), 256, 0, stream>>>(eig + Eg, off_g, list_g, Eg);
    // ---- CSR build: lg-graph (dst over g-edges) ----
    hipMemsetAsync(off_lg, 0, (size_t)(Eg + 1) * 4, stream);
    count_kernel<<<(int)((Elg + 255) / 256), 256, 0, stream>>>(eilg + Elg, off_lg, Elg);
    {
        int nb = (int)((Eg + 1023) / 1024);
        scan1<<<nb, 256, 0, stream>>>(off_lg, part, (int)Eg);
        scan2<<<1, 1024, 0, stream>>>(part, nb, off_lg + Eg);
        scan3<<<nb, 256, 0, stream>>>(off_lg, part, (int)Eg);
    }
    fill_kernel<<<(int)((Elg + 255) / 256), 256, 0, stream>>>(eilg + Elg, off_lg, list_lg, Elg);

    // jk0 = relu(x @ W_feat^T)
    rowgemm<128, true, false><<<(N + 63) / 64, 256, 0, stream>>>(
        x, W_feat, nullptr, nullptr, jkB, N);
    // initial msgs -> mA (plain stores)
    edge_msg_init2<<<(int)((Eg + 127) / 128), 512, 0, stream>>>(
        jkB, eig, eag, W_msg, mA, Eg);
    // jk1 = gather(mA) @ W_lg2g^T + deg*b
    gather_g<<<(N + 7) / 8, 256, 0, stream>>>(mA, list_g, off_g, aggB, deg, N);
    rowgemm<64, false, true><<<(N + 63) / 64, 256, 0, stream>>>(
        aggB, W_lg2g, b_lg2g, deg, jkB + (size_t)N * 64, N);
    // ---- linegraph layer 0: mA -> mB ----
    zero_fill<<<(int)((Eg * 8 + 255) / 256), 256, 0, stream>>>(off_lg, mB, Eg);
    edge_msg_lg2<<<(int)((Elg + 127) / 128), 512, 0, stream>>>(
        mA, eilg, ealg, W_msg_l, list_lg, mB, Elg);
    gather_g<<<(N + 7) / 8, 256, 0, stream>>>(mB, list_g, off_g, aggB, nullptr, N);
    rowgemm<64, false, true><<<(N + 63) / 64, 256, 0, stream>>>(
        aggB, W_lg2g, b_lg2g, nullptr, jkB + (size_t)2 * N * 64, N);
    // ---- linegraph layer 1: mB -> mA ----
    zero_fill<<<(int)((Eg * 8 + 255) / 256), 256, 0, stream>>>(off_lg, mA, Eg);
    edge_msg_lg2<<<(int)((Elg + 127) / 128), 512, 0, stream>>>(
        mB, eilg, ealg, W_msg_l + 64 * 144, list_lg, mA, Elg);
    gather_g<<<(N + 7) / 8, 256, 0, stream>>>(mA, list_g, off_g, aggB, nullptr, N);
    rowgemm<64, false, true><<<(N + 63) / 64, 256, 0, stream>>>(
        aggB, W_lg2g, b_lg2g, nullptr, jkB + (size_t)3 * N * 64, N);
    // ---- JK bidirectional LSTM (one 64-node tile per block) ----
    {
        int ntiles = (N + 63) / 64;
        lstm3<<<dim3(ntiles, 2), 512, 0, stream>>>(
            jkB, WhhB, WihB, BS, W_att, scores, N);
    }
    final_kernel<<<(N + 3) / 4, 256, 0, stream>>>(
        jkB, scores, W_out, (float*)d_out, N);
}